// Round 2
// baseline (508.666 us; speedup 1.0000x reference)
//
#include <hip/hip_runtime.h>

// Reference: dynamic_partition + dynamic_stitch with the same permutation
// => out == data exactly (identity). Pure 1 GiB d2d copy, memory-bound.
//
// R1: 4x ILP unroll — 4 independent global_load_dwordx4 in flight per wave
// before the stores, to cover ~900-cycle HBM latency without relying on
// perfect wave interleave. Stride-separated addresses keep full coalescing.

__global__ __launch_bounds__(256) void copy_f4x4_kernel(const float4* __restrict__ in,
                                                        float4* __restrict__ out,
                                                        long long n4) {
    const long long stride = (long long)gridDim.x * blockDim.x;
    long long i = (long long)blockIdx.x * blockDim.x + threadIdx.x;

    // main unrolled loop: 4 independent loads, then 4 stores
    for (; i + 3 * stride < n4; i += 4 * stride) {
        float4 a = in[i];
        float4 b = in[i + stride];
        float4 c = in[i + 2 * stride];
        float4 d = in[i + 3 * stride];
        out[i]              = a;
        out[i + stride]     = b;
        out[i + 2 * stride] = c;
        out[i + 3 * stride] = d;
    }
    // tail (not taken for n4 = 64M with this grid, kept for safety)
    for (; i < n4; i += stride) {
        out[i] = in[i];
    }
}

extern "C" void kernel_launch(void* const* d_in, const int* in_sizes, int n_in,
                              void* d_out, int out_size, void* d_ws, size_t ws_size,
                              hipStream_t stream) {
    const float4* data = (const float4*)d_in[0];
    float4* out = (float4*)d_out;
    long long n = (long long)in_sizes[0];   // 268,435,456 floats (N*D), divisible by 4
    long long n4 = n / 4;

    const int block = 256;
    const int grid = 2048;  // 256 CUs * 8 blocks/CU; 128 iters/thread, no tail
    copy_f4x4_kernel<<<grid, block, 0, stream>>>(data, out, n4);
}

// Round 4
// 426.616 us; speedup vs baseline: 1.1923x; 1.1923x over previous
//
#include <hip/hip_runtime.h>

// Reference: dynamic_partition + dynamic_stitch with the same permutation
// => out == data exactly (identity). Pure 1 GiB d2d copy, memory-bound.
//
// R3: R2 retry — nontemporal builtins need a NATIVE clang vector type,
// not HIP_vector_type<float,4>. Use ext_vector_type(4) float.

typedef float f4 __attribute__((ext_vector_type(4)));

__global__ __launch_bounds__(256) void copy_f4_nt_kernel(const f4* __restrict__ in,
                                                         f4* __restrict__ out,
                                                         long long n4) {
    const long long stride = (long long)gridDim.x * blockDim.x;
    for (long long i = (long long)blockIdx.x * blockDim.x + threadIdx.x; i < n4; i += stride) {
        f4 v = __builtin_nontemporal_load(&in[i]);
        __builtin_nontemporal_store(v, &out[i]);
    }
}

extern "C" void kernel_launch(void* const* d_in, const int* in_sizes, int n_in,
                              void* d_out, int out_size, void* d_ws, size_t ws_size,
                              hipStream_t stream) {
    const f4* data = (const f4*)d_in[0];
    f4* out = (f4*)d_out;
    long long n = (long long)in_sizes[0];   // 268,435,456 floats (N*D)
    long long n4 = n / 4;

    const int block = 256;
    const int grid = 2048;  // 256 CUs * 8 blocks/CU; 128 iters/thread
    copy_f4_nt_kernel<<<grid, block, 0, stream>>>(data, out, n4);
}

// Round 5
// 334.183 us; speedup vs baseline: 1.5221x; 1.2766x over previous
//
#include <hip/hip_runtime.h>

// Reference: dynamic_partition + dynamic_stitch with the same permutation
// => out == data exactly (identity). Pure 1 GiB d2d copy, memory-bound.
//
// R4: fill-kernel style — one float4 per thread, flat grid (262,144 blocks),
// nontemporal load+store. Each block owns a contiguous 4 KB chunk; HW
// dispatches blocks in address order -> best DRAM locality, zero loop
// overhead between dependent memory ops.

typedef float f4 __attribute__((ext_vector_type(4)));

__global__ __launch_bounds__(256) void copy_f4_flat_nt_kernel(const f4* __restrict__ in,
                                                              f4* __restrict__ out,
                                                              long long n4) {
    long long i = (long long)blockIdx.x * blockDim.x + threadIdx.x;
    if (i < n4) {
        f4 v = __builtin_nontemporal_load(&in[i]);
        __builtin_nontemporal_store(v, &out[i]);
    }
}

extern "C" void kernel_launch(void* const* d_in, const int* in_sizes, int n_in,
                              void* d_out, int out_size, void* d_ws, size_t ws_size,
                              hipStream_t stream) {
    const f4* data = (const f4*)d_in[0];
    f4* out = (f4*)d_out;
    long long n = (long long)in_sizes[0];   // 268,435,456 floats (N*D)
    long long n4 = n / 4;                   // 67,108,864 float4s

    const int block = 256;
    long long grid = (n4 + block - 1) / block;  // 262,144 blocks
    copy_f4_flat_nt_kernel<<<(int)grid, block, 0, stream>>>(data, out, n4);
}